// Round 1
// baseline (500.752 us; speedup 1.0000x reference)
//
#include <hip/hip_runtime.h>
#include <hip/hip_bf16.h>
#include <cstdint>

typedef __bf16 bf16x8 __attribute__((ext_vector_type(8)));
typedef float f32x4 __attribute__((ext_vector_type(4)));

// Q pre-scale: (1/sqrt(768)) * log2(e)  -> attention exp becomes raw exp2
#define SCALE_Q_LOG2E 0.052058770734702875f

// fast exp2 via v_exp_f32 (NOTE: __exp2f collides with glibc math.h macro)
__device__ inline float fast_exp2(float x) { return __builtin_amdgcn_exp2f(x); }

// ---------------------------------------------------------------------------
// prep kernel: 5 weight transposes (fp32->bf16, dst[n][k]=src[k][n]) PLUS
// t-path stage 1 ([2,768]@[768,4608] k-split atomic) in one dispatch.
// ---------------------------------------------------------------------------
struct PrepArgs {
  const float* src[5];
  __hip_bfloat16* dst[5];
  int K[5], N[5];
  int start[6];           // transpose block ranges; start[5] = total transpose blocks
  const float* tin;       // t input [2,768]
  const float* w_ss1;     // [768,4608]
  float* tacc1;           // [2,4608] (zeroed)
};

__global__ void k_prep(PrepArgs pa) {
  __shared__ float tile[32][33];
  int bid = blockIdx.x;
  int tid = threadIdx.x;
  if (bid < pa.start[5]) {
    int i = 0;
#pragma unroll
    for (int j = 1; j < 5; ++j)
      if (bid >= pa.start[j]) i = j;
    int t0 = bid - pa.start[i];
    int N = pa.N[i], K = pa.K[i];
    int ntx = N >> 5;
    int bx = t0 % ntx, by = t0 / ntx;
    const float* src = pa.src[i];
    __hip_bfloat16* dst = pa.dst[i];
    int n0 = bx * 32, k0 = by * 32;
    int tx = tid & 31, ty = tid >> 5;  // 32 x 8
#pragma unroll
    for (int r = 0; r < 32; r += 8)
      tile[ty + r][tx] = src[(size_t)(k0 + ty + r) * N + n0 + tx];
    __syncthreads();
#pragma unroll
    for (int r = 0; r < 32; r += 8)
      dst[(size_t)(n0 + ty + r) * K + k0 + tx] = __float2bfloat16(tile[tx][ty + r]);
  } else {
    int t0 = bid - pa.start[5];
    int nb = t0 % 18, kb0 = (t0 / 18) * 64;
    int n = nb * 256 + tid;
    float a0 = 0.f, a1 = 0.f;
    for (int k = kb0; k < kb0 + 64; ++k) {
      float w = pa.w_ss1[(size_t)k * 4608 + n];
      a0 += pa.tin[k] * w;
      a1 += pa.tin[768 + k] * w;
    }
    atomicAdd(&pa.tacc1[n], a0);
    atomicAdd(&pa.tacc1[4608 + n], a1);
  }
}

// ---------------------------------------------------------------------------
// t-path stage 2 with inline silu+bias on the input:
// teacc[b][n] += sum_k silu(tacc1[b][k]+b_ss1[k]) * w_ss2[k][n]
// ---------------------------------------------------------------------------
__global__ void k_tvec2_silu(const float* __restrict__ tacc1, const float* __restrict__ bss1,
                             const float* __restrict__ W, float* __restrict__ teacc) {
  int n = blockIdx.x * 256 + threadIdx.x;
  int kb = blockIdx.y * 64;
  float a0 = 0.f, a1 = 0.f;
  for (int k = kb; k < kb + 64; ++k) {
    float w = W[(size_t)k * 4608 + n];
    float bs = bss1[k];
    float t0 = tacc1[k] + bs;
    float t1 = tacc1[4608 + k] + bs;
    t0 = t0 / (1.f + expf(-t0));
    t1 = t1 / (1.f + expf(-t1));
    a0 += t0 * w;
    a1 += t1 * w;
  }
  atomicAdd(&teacc[n], a0);
  atomicAdd(&teacc[4608 + n], a1);
}

// ---------------------------------------------------------------------------
// LayerNorm + adaLN modulate: out_bf16 = (teacc+bss2)[g] * LN(x) + (teacc+bss2)[b]
// ---------------------------------------------------------------------------
__global__ void k_ln_mod(const float* __restrict__ x, const float* __restrict__ lng,
                         const float* __restrict__ lnb, const float* __restrict__ teacc,
                         const float* __restrict__ bss2,
                         int gofs, int bofs, __hip_bfloat16* __restrict__ out) {
  int row = blockIdx.x;          // 0..4095
  int b = row >> 11;             // / 2048
  const float* xr = x + (size_t)row * 768;
  int tid = threadIdx.x;
  float v[3];
  float s = 0.f, sq = 0.f;
#pragma unroll
  for (int i = 0; i < 3; ++i) { v[i] = xr[tid + 256 * i]; s += v[i]; sq += v[i] * v[i]; }
#pragma unroll
  for (int o = 32; o > 0; o >>= 1) { s += __shfl_xor(s, o); sq += __shfl_xor(sq, o); }
  __shared__ float rs[4], rq[4];
  int w = tid >> 6, lane = tid & 63;
  if (lane == 0) { rs[w] = s; rq[w] = sq; }
  __syncthreads();
  s = rs[0] + rs[1] + rs[2] + rs[3];
  sq = rq[0] + rq[1] + rq[2] + rq[3];
  float mu = s * (1.f / 768.f);
  float var = sq * (1.f / 768.f) - mu * mu;
  float rstd = rsqrtf(var + 1e-5f);
  const float* tb = teacc + (size_t)b * 4608;
#pragma unroll
  for (int i = 0; i < 3; ++i) {
    int n = tid + 256 * i;
    float gv = tb[gofs + n] + bss2[gofs + n];
    float bv = tb[bofs + n] + bss2[bofs + n];
    float h = (v[i] - mu) * rstd * lng[n] + lnb[n];
    h = gv * h + bv;
    out[(size_t)row * 768 + n] = __float2bfloat16(h);
  }
}

// ---------------------------------------------------------------------------
// m97-style bf16 MFMA GEMM: C[M,N] = A[M,K] @ Bt[N,K]^T (both [row][k]).
// Tile BM x BN, BK=64, 4 waves (2x2), global_load_lds width=16 staging,
// XOR-swizzled LDS (phys_chunk = logical ^ (row&7)).
// Epilogues: 0=bias->f32, 1=bias+gelu(tanh)->bf16, 2=res+gate*(acc+bias)->f32
//            3=qkv fused: Q scaled ->qkvb, K ->qkvb, V -> VT transposed
// ---------------------------------------------------------------------------
template <int BM, int BN, int EPI>
__global__ __launch_bounds__(256)
void k_gemm(const __hip_bfloat16* __restrict__ A,
            const __hip_bfloat16* __restrict__ Bt,
            const float* __restrict__ bias,
            float* __restrict__ outF, __hip_bfloat16* __restrict__ outB,
            __hip_bfloat16* __restrict__ outV,
            const float* __restrict__ res, const float* __restrict__ teacc,
            const float* __restrict__ bss2,
            int gofs, int M, int N, int K) {
  constexpr int MI = BM / 32;
  constexpr int NI = BN / 32;
  __shared__ __align__(16) __hip_bfloat16 As[BM * 64];
  __shared__ __align__(16) __hip_bfloat16 Bs[BN * 64];
  const int tid = threadIdx.x;
  const int w = tid >> 6, lane = tid & 63;
  const int quad = lane >> 4, l16 = lane & 15;
  const int wm = w & 1, wn = w >> 1;
  const int m0 = blockIdx.y * BM, n0 = blockIdx.x * BN;
  const int srow = lane >> 3;
  const int sco = ((lane & 7) ^ srow) * 8;

  f32x4 acc[MI][NI] = {};

  for (int k0 = 0; k0 < K; k0 += 64) {
#pragma unroll
    for (int ii = 0; ii < BM / 32; ++ii) {
      int is = w * (BM / 32) + ii;
      const __hip_bfloat16* g = A + (size_t)(m0 + is * 8 + srow) * K + k0 + sco;
      __builtin_amdgcn_global_load_lds(
          (const __attribute__((address_space(1))) void*)g,
          (__attribute__((address_space(3))) void*)&As[is * 512], 16, 0, 0);
    }
#pragma unroll
    for (int ii = 0; ii < BN / 32; ++ii) {
      int is = w * (BN / 32) + ii;
      const __hip_bfloat16* g = Bt + (size_t)(n0 + is * 8 + srow) * K + k0 + sco;
      __builtin_amdgcn_global_load_lds(
          (const __attribute__((address_space(1))) void*)g,
          (__attribute__((address_space(3))) void*)&Bs[is * 512], 16, 0, 0);
    }
    __syncthreads();
#pragma unroll
    for (int ks = 0; ks < 2; ++ks) {
      bf16x8 af[MI], bfv[NI];
#pragma unroll
      for (int i = 0; i < MI; ++i) {
        int row = wm * (BM / 2) + i * 16 + l16;
        int cph = (ks * 4 + quad) ^ (row & 7);
        af[i] = *(const bf16x8*)&As[row * 64 + cph * 8];
      }
#pragma unroll
      for (int j = 0; j < NI; ++j) {
        int row = wn * (BN / 2) + j * 16 + l16;
        int cph = (ks * 4 + quad) ^ (row & 7);
        bfv[j] = *(const bf16x8*)&Bs[row * 64 + cph * 8];
      }
#pragma unroll
      for (int i = 0; i < MI; ++i)
#pragma unroll
        for (int j = 0; j < NI; ++j)
          acc[i][j] = __builtin_amdgcn_mfma_f32_16x16x32_bf16(af[i], bfv[j], acc[i][j], 0, 0, 0);
    }
    __syncthreads();
  }

#pragma unroll
  for (int j = 0; j < NI; ++j) {
    int col = n0 + wn * (BN / 2) + j * 16 + l16;
    float bs = bias[col];
#pragma unroll
    for (int i = 0; i < MI; ++i) {
      int row0 = m0 + wm * (BM / 2) + i * 16 + quad * 4;
      if (EPI == 3 && col >= 1536) {
        // V head: write transposed into VT[(b*12+nh)*64+dl][token], 8B packed
        int d = col - 1536;
        int nh = d >> 6, dl = d & 63;
        int bb = row0 >> 11, tok = row0 & 2047;
        __hip_bfloat16 tmp[4];
#pragma unroll
        for (int r = 0; r < 4; ++r) tmp[r] = __float2bfloat16(acc[i][j][r] + bs);
        *(uint2*)&outV[((size_t)(bb * 12 + nh) * 64 + dl) * 2048 + tok] = *(uint2*)tmp;
      } else {
#pragma unroll
        for (int r = 0; r < 4; ++r) {
          int row = row0 + r;
          float v = acc[i][j][r] + bs;
          size_t idx = (size_t)row * N + col;
          if (EPI == 0) {
            outF[idx] = v;
          } else if (EPI == 1) {
            // tanh-approx gelu: v - v/(e+1), e = exp2(2*log2e*0.79788456*(v+0.044715 v^3))
            float v2 = v * v;
            float u = v * (0.79788456080286536f + 0.035677408136300125f * v2);
            float e = fast_exp2(u * 2.8853900817779268f);
            float gl = v - v * __builtin_amdgcn_rcpf(e + 1.f);
            outB[idx] = __float2bfloat16(gl);
          } else if (EPI == 2) {
            float gate = teacc[(size_t)(row >> 11) * 4608 + gofs + col] + bss2[gofs + col];
            outF[idx] = res[idx] + gate * v;
          } else {  // EPI==3, Q/K heads
            float vq = (col < 768) ? v * SCALE_Q_LOG2E : v;
            outB[idx] = __float2bfloat16(vq);
          }
        }
      }
    }
  }
}

// ---------------------------------------------------------------------------
// MFMA flash attention — counted-vmcnt pipelined version.
// Changes vs round-6 (59.6 us, MfmaUtil 19.6%):
//  * Ks double-buffered (Ks[2]); V[kt] + K[kt+1] issued at top of tile kt so
//    staging latency hides under QK^T (K) and QK^T+exp2/P-pack (V).
//  * Raw s_barrier + counted s_waitcnt vmcnt(8)/vmcnt(4) (never 0 in steady
//    state) instead of __syncthreads' full vmcnt(0) drain.
//    Ledger (per wave): top-of-loop outstanding = 4 (K[kt]); after issuing
//    V(4)+K[kt+1](4) = 12; vmcnt(8) retires K[kt]; pre-PV vmcnt(4) retires
//    V[kt], leaving K[kt+1] in flight across the barrier.
//  * Per-wave P buffer aliased into Ks[cur] (wave w's K-staging region ==
//    rows 32w..32w+31 == its 4KB P region), legal after the post-QK^T
//    barrier. LDS stays 48KB -> 3 blocks/CU preserved.
//  * s_setprio(1) around the MFMA clusters (T5; attn-positive per m191).
// ---------------------------------------------------------------------------
__launch_bounds__(256)
__global__ void k_attn(const __hip_bfloat16* __restrict__ qkvb,
                       const __hip_bfloat16* __restrict__ VT,
                       __hip_bfloat16* __restrict__ out) {
  __shared__ __align__(16) __hip_bfloat16 Ks[2][128 * 64];  // [s][d], 8-chunk swizzle; Ks[cur] doubles as P
  __shared__ __align__(16) __hip_bfloat16 Vs[64 * 128];     // [d][s], 16-chunk swizzle

  const int tid = threadIdx.x;
  const int w = tid >> 6, lane = tid & 63;
  const int quad = lane >> 4, l16 = lane & 15;
  const int qt = blockIdx.x, nh = blockIdx.y, b = blockIdx.z;
  const int bh = b * 12 + nh;

  const int qrow0 = b * 2048 + qt * 64 + w * 16;
  bf16x8 qf[2];
#pragma unroll
  for (int t = 0; t < 2; ++t)
    qf[t] = *(const bf16x8*)(qkvb + (size_t)(qrow0 + l16) * 2304 + nh * 64 + t * 32 + quad * 8);
  // Retire the Q loads now so the in-loop vmcnt ledger counts only staging.
  asm volatile("s_waitcnt vmcnt(0)" ::: "memory");

  bf16x8 ones;
#pragma unroll
  for (int j = 0; j < 8; ++j) ones[j] = (__bf16)1.0f;

  f32x4 o[4] = {};   // col = nf*16+l16, row = quad*4+r
  f32x4 o_l = {};    // row sums (replicated over cols)

  const int srow8 = lane >> 3;               // K staging: 8 rows/instr
  const int sco8 = ((lane & 7) ^ srow8) * 8;
  const int srow4 = lane >> 4;               // V staging: 4 rows/instr

  // prologue: stage K[0] -> Ks[0]   (outstanding: 4)
#pragma unroll
  for (int ii = 0; ii < 4; ++ii) {
    int i = w * 4 + ii;
    const __hip_bfloat16* gk =
        qkvb + (size_t)(b * 2048 + i * 8 + srow8) * 2304 + 768 + nh * 64 + sco8;
    __builtin_amdgcn_global_load_lds(
        (const __attribute__((address_space(1))) void*)gk,
        (__attribute__((address_space(3))) void*)&Ks[0][i * 512], 16, 0, 0);
  }

#pragma unroll 1
  for (int kt = 0; kt < 16; ++kt) {
    const int cur = kt & 1;

    // B_consume: all waves done reading Vs / P-in-Ks[cur^1] from prev tile.
    asm volatile("s_waitcnt lgkmcnt(0)" ::: "memory");
    __builtin_amdgcn_s_barrier();

    // issue V[kt] -> Vs              (outstanding: 4 -> 8)
#pragma unroll
    for (int ii = 0; ii < 4; ++ii) {
      int i = w * 4 + ii;
      int vrow = i * 4 + srow4;
      const __hip_bfloat16* gv =
          VT + (size_t)(bh * 64 + vrow) * 2048 + kt * 128 + (((lane & 15) ^ (vrow & 15)) * 8);
      __builtin_amdgcn_global_load_lds(
          (const __attribute__((address_space(1))) void*)gv,
          (__attribute__((address_space(3))) void*)&Vs[i * 512], 16, 0, 0);
    }
    // issue K[kt+1] -> Ks[cur^1]     (outstanding: 8 -> 12)
    if (kt < 15) {
#pragma unroll
      for (int ii = 0; ii < 4; ++ii) {
        int i = w * 4 + ii;
        const __hip_bfloat16* gk =
            qkvb + (size_t)(b * 2048 + (kt + 1) * 128 + i * 8 + srow8) * 2304 + 768 + nh * 64 + sco8;
        __builtin_amdgcn_global_load_lds(
            (const __attribute__((address_space(1))) void*)gk,
            (__attribute__((address_space(3))) void*)&Ks[cur ^ 1][i * 512], 16, 0, 0);
      }
      asm volatile("s_waitcnt vmcnt(8)" ::: "memory");   // K[kt] retired
    } else {
      asm volatile("s_waitcnt vmcnt(4)" ::: "memory");   // K[15] retired (only V in flight)
    }
    __builtin_amdgcn_s_barrier();                        // B_Kready

    // ---- S = Q K^T : 16 q-rows x 128 s-cols per wave ----
    f32x4 s_acc[8] = {};
    __builtin_amdgcn_s_setprio(1);
#pragma unroll
    for (int t = 0; t < 2; ++t) {
#pragma unroll
      for (int c = 0; c < 8; ++c) {
        int row = c * 16 + l16;
        int cph = (t * 4 + quad) ^ (row & 7);
        bf16x8 kf = *(const bf16x8*)&Ks[cur][row * 64 + cph * 8];
        s_acc[c] = __builtin_amdgcn_mfma_f32_16x16x32_bf16(qf[t], kf, s_acc[c], 0, 0, 0);
      }
    }
    __builtin_amdgcn_s_setprio(0);

    // B_QKdone: all waves finished reading Ks[cur]; it may now take P.
    asm volatile("s_waitcnt lgkmcnt(0)" ::: "memory");
    __builtin_amdgcn_s_barrier();

    // ---- P = exp2(S') -> per-wave region of Ks[cur] (swizzled writes) ----
    __hip_bfloat16* Pb = &Ks[cur][w * 2048];
#pragma unroll
    for (int c = 0; c < 8; ++c) {
      int chunk = c * 2 + (l16 >> 3);
#pragma unroll
      for (int r = 0; r < 4; ++r) {
        float p = fast_exp2(s_acc[c][r]);
        int row = quad * 4 + r;
        int phys = chunk ^ row;
        Pb[row * 128 + phys * 8 + (l16 & 7)] = __float2bfloat16(p);
      }
    }

    // V[kt] retired (K[kt+1] stays in flight across the barrier); own P visible.
    if (kt < 15) asm volatile("s_waitcnt vmcnt(4)" ::: "memory");
    else         asm volatile("s_waitcnt vmcnt(0)" ::: "memory");
    asm volatile("s_waitcnt lgkmcnt(0)" ::: "memory");
    __builtin_amdgcn_s_barrier();                        // B_Vready

    // ---- O += P V, l += P @ ones ----
    __builtin_amdgcn_s_setprio(1);
#pragma unroll
    for (int t2 = 0; t2 < 4; ++t2) {
      int phys_p = ((t2 * 4 + quad) ^ l16);
      bf16x8 pa = *(const bf16x8*)&Pb[l16 * 128 + phys_p * 8];
#pragma unroll
      for (int nf = 0; nf < 4; ++nf) {
        int row = nf * 16 + l16;
        int cph = (t2 * 4 + quad) ^ (row & 15);
        bf16x8 vf = *(const bf16x8*)&Vs[row * 128 + cph * 8];
        o[nf] = __builtin_amdgcn_mfma_f32_16x16x32_bf16(pa, vf, o[nf], 0, 0, 0);
      }
      o_l = __builtin_amdgcn_mfma_f32_16x16x32_bf16(pa, ones, o_l, 0, 0, 0);
    }
    __builtin_amdgcn_s_setprio(0);
  }

  // ---- epilogue: O / l ----
  {
    float inv[4];
#pragma unroll
    for (int r = 0; r < 4; ++r) inv[r] = 1.f / o_l[r];
#pragma unroll
    for (int nf = 0; nf < 4; ++nf)
#pragma unroll
      for (int r = 0; r < 4; ++r) {
        int row = qrow0 + quad * 4 + r;
        out[(size_t)row * 768 + nh * 64 + nf * 16 + l16] = __float2bfloat16(o[nf][r] * inv[r]);
      }
  }
}

// ---------------------------------------------------------------------------
extern "C" void kernel_launch(void* const* d_in, const int* in_sizes, int n_in,
                              void* d_out, int out_size, void* d_ws, size_t ws_size,
                              hipStream_t stream) {
  const float* x      = (const float*)d_in[0];
  const float* t      = (const float*)d_in[1];
  const float* w_qkv  = (const float*)d_in[2];
  const float* b_qkv  = (const float*)d_in[3];
  const float* w_m1   = (const float*)d_in[4];
  const float* b_m1   = (const float*)d_in[5];
  const float* w_m2   = (const float*)d_in[6];
  const float* b_m2   = (const float*)d_in[7];
  const float* w_ss1  = (const float*)d_in[8];
  const float* b_ss1  = (const float*)d_in[9];
  const float* w_ss2  = (const float*)d_in[10];
  const float* b_ss2  = (const float*)d_in[11];
  const float* ln1_g  = (const float*)d_in[12];
  const float* ln1_b  = (const float*)d_in[13];
  const float* ln2_g  = (const float*)d_in[14];
  const float* ln2_b  = (const float*)d_in[15];
  const float* w_f1   = (const float*)d_in[16];
  const float* b_f1   = (const float*)d_in[17];
  const float* w_f2   = (const float*)d_in[18];
  const float* b_f2   = (const float*)d_in[19];
  float* out = (float*)d_out;

  char* ws = (char*)d_ws;
  size_t off = 0;
  auto alloc = [&](size_t bytes) -> char* {
    off = (off + 255) & ~(size_t)255;
    char* p = ws + off;
    off += bytes;
    return p;
  };
  __hip_bfloat16* wtq  = (__hip_bfloat16*)alloc((size_t)2304 * 768 * 2);
  __hip_bfloat16* wtm1 = (__hip_bfloat16*)alloc((size_t)3072 * 768 * 2);
  __hip_bfloat16* wtm2 = (__hip_bfloat16*)alloc((size_t)768 * 3072 * 2);
  __hip_bfloat16* wtf1 = (__hip_bfloat16*)alloc((size_t)3072 * 768 * 2);
  __hip_bfloat16* wtf2 = (__hip_bfloat16*)alloc((size_t)768 * 3072 * 2);
  float* tacc1 = (float*)alloc(9216 * 4);
  float* teacc = (float*)alloc(9216 * 4);
  __hip_bfloat16* h1   = (__hip_bfloat16*)alloc((size_t)4096 * 768 * 2);   // reused as h2
  __hip_bfloat16* qkvb = (__hip_bfloat16*)alloc((size_t)4096 * 2304 * 2);
  __hip_bfloat16* VT   = (__hip_bfloat16*)alloc((size_t)24 * 64 * 2048 * 2);
  __hip_bfloat16* attn = (__hip_bfloat16*)alloc((size_t)4096 * 768 * 2);
  __hip_bfloat16* act1 = (__hip_bfloat16*)alloc((size_t)4096 * 3072 * 2);  // reused as act2
  float* x1            = (float*)alloc((size_t)4096 * 768 * 4);

  (void)hipMemsetAsync(tacc1, 0, 9216 * 4, stream);
  (void)hipMemsetAsync(teacc, 0, 9216 * 4, stream);

  // prep: 5 weight transposes + t-path stage 1
  PrepArgs pa;
  pa.src[0] = w_qkv; pa.dst[0] = wtq;  pa.K[0] = 768;  pa.N[0] = 2304;
  pa.src[1] = w_m1;  pa.dst[1] = wtm1; pa.K[1] = 768;  pa.N[1] = 3072;
  pa.src[2] = w_m2;  pa.dst[2] = wtm2; pa.K[2] = 3072; pa.N[2] = 768;
  pa.src[3] = w_f1;  pa.dst[3] = wtf1; pa.K[3] = 768;  pa.N[3] = 3072;
  pa.src[4] = w_f2;  pa.dst[4] = wtf2; pa.K[4] = 3072; pa.N[4] = 768;
  pa.start[0] = 0;
  pa.start[1] = pa.start[0] + (2304 / 32) * (768 / 32);
  pa.start[2] = pa.start[1] + (3072 / 32) * (768 / 32);
  pa.start[3] = pa.start[2] + (768 / 32) * (3072 / 32);
  pa.start[4] = pa.start[3] + (3072 / 32) * (768 / 32);
  pa.start[5] = pa.start[4] + (768 / 32) * (3072 / 32);
  pa.tin = t; pa.w_ss1 = w_ss1; pa.tacc1 = tacc1;
  int tvec1_blocks = 18 * 12;  // (4608/256) x (768/64)
  k_prep<<<pa.start[5] + tvec1_blocks, 256, 0, stream>>>(pa);

  // t-path stage 2 (silu+bias inline)
  k_tvec2_silu<<<dim3(4608 / 256, 4608 / 64), 256, 0, stream>>>(tacc1, b_ss1, w_ss2, teacc);

  // block 1: LN1+mod -> qkv GEMM (Q scaled, V transposed to VT) -> attn -> mFFN
  k_ln_mod<<<4096, 256, 0, stream>>>(x, ln1_g, ln1_b, teacc, b_ss2, 0, 768, h1);
  k_gemm<64, 128, 3><<<dim3(2304 / 128, 4096 / 64), 256, 0, stream>>>(
      h1, wtq, b_qkv, nullptr, qkvb, VT, nullptr, nullptr, nullptr, 0, 4096, 2304, 768);
  k_attn<<<dim3(32, 12, 2), 256, 0, stream>>>(qkvb, VT, attn);
  k_gemm<128, 128, 1><<<dim3(3072 / 128, 4096 / 128), 256, 0, stream>>>(
      attn, wtm1, b_m1, nullptr, act1, nullptr, nullptr, nullptr, nullptr, 0, 4096, 3072, 768);
  k_gemm<64, 128, 2><<<dim3(768 / 128, 4096 / 64), 256, 0, stream>>>(
      act1, wtm2, b_m2, x1, nullptr, nullptr, x, teacc, b_ss2, 1536, 4096, 768, 3072);

  // block 2: LN2+mod -> FFN
  k_ln_mod<<<4096, 256, 0, stream>>>(x1, ln2_g, ln2_b, teacc, b_ss2, 2304, 3072, h1);
  k_gemm<128, 128, 1><<<dim3(3072 / 128, 4096 / 128), 256, 0, stream>>>(
      h1, wtf1, b_f1, nullptr, act1, nullptr, nullptr, nullptr, nullptr, 0, 4096, 3072, 768);
  k_gemm<64, 128, 2><<<dim3(768 / 128, 4096 / 64), 256, 0, stream>>>(
      act1, wtf2, b_f2, out, nullptr, nullptr, x1, teacc, b_ss2, 3840, 4096, 768, 3072);
}

// Round 2
// 470.225 us; speedup vs baseline: 1.0649x; 1.0649x over previous
//
#include <hip/hip_runtime.h>
#include <hip/hip_bf16.h>
#include <cstdint>

typedef __bf16 bf16x8 __attribute__((ext_vector_type(8)));
typedef float f32x4 __attribute__((ext_vector_type(4)));

// Q pre-scale: (1/sqrt(768)) * log2(e)  -> attention exp becomes raw exp2
#define SCALE_Q_LOG2E 0.052058770734702875f

// fast exp2 via v_exp_f32 (NOTE: __exp2f collides with glibc math.h macro)
__device__ inline float fast_exp2(float x) { return __builtin_amdgcn_exp2f(x); }

// ---------------------------------------------------------------------------
// prep kernel: 5 weight transposes (fp32->bf16, dst[n][k]=src[k][n]) PLUS
// t-path stage 1 ([2,768]@[768,4608] k-split atomic) in one dispatch.
// Round-2 rewrite: 64x64 tiles, float4 loads (16B/lane), uint2 bf16 stores
// (8B/lane). Old 32x32 scalar version was latency-bound at 950 GB/s / 55 us
// (VALUBusy 5.5%, occupancy 31%): only 16B in flight per thread.
// LDS tile[64][65]: both access phases are exactly 2-way bank-aliased (free).
// ---------------------------------------------------------------------------
struct PrepArgs {
  const float* src[5];
  __hip_bfloat16* dst[5];
  int K[5], N[5];
  int start[6];           // transpose block ranges; start[5] = total transpose blocks
  const float* tin;       // t input [2,768]
  const float* w_ss1;     // [768,4608]
  float* tacc1;           // [2,4608] (zeroed)
};

__global__ __launch_bounds__(256) void k_prep(PrepArgs pa) {
  __shared__ float tile[64][65];
  int bid = blockIdx.x;
  int tid = threadIdx.x;
  if (bid < pa.start[5]) {
    int i = 0;
#pragma unroll
    for (int j = 1; j < 5; ++j)
      if (bid >= pa.start[j]) i = j;
    int t0 = bid - pa.start[i];
    int N = pa.N[i], K = pa.K[i];
    int ntx = N >> 6;
    int bx = t0 % ntx, by = t0 / ntx;
    const float* src = pa.src[i];
    __hip_bfloat16* dst = pa.dst[i];
    int n0 = bx * 64, k0 = by * 64;
    // ---- load 64x64 fp32 tile, float4 per thread, 4 rows-groups ----
    int c4 = tid & 15, rr = tid >> 4;   // 16 float4-cols x 16 rows per pass
    float4 v[4];
#pragma unroll
    for (int p = 0; p < 4; ++p)
      v[p] = *(const float4*)&src[(size_t)(k0 + rr + 16 * p) * N + n0 + c4 * 4];
#pragma unroll
    for (int p = 0; p < 4; ++p) {
      tile[rr + 16 * p][c4 * 4 + 0] = v[p].x;
      tile[rr + 16 * p][c4 * 4 + 1] = v[p].y;
      tile[rr + 16 * p][c4 * 4 + 2] = v[p].z;
      tile[rr + 16 * p][c4 * 4 + 3] = v[p].w;
    }
    __syncthreads();
    // ---- write 64 n-rows of 64 k, 4 bf16 packed per thread (uint2) ----
    int kg = tid & 15, nl = tid >> 4;
#pragma unroll
    for (int p = 0; p < 4; ++p) {
      int n = nl + 16 * p;
      __hip_bfloat16 t4[4];
#pragma unroll
      for (int j = 0; j < 4; ++j) t4[j] = __float2bfloat16(tile[kg * 4 + j][n]);
      *(uint2*)&dst[(size_t)(n0 + n) * K + k0 + kg * 4] = *(uint2*)t4;
    }
  } else {
    int t0 = bid - pa.start[5];
    int nb = t0 % 18, kb0 = (t0 / 18) * 64;
    int n = nb * 256 + tid;
    float a0 = 0.f, a1 = 0.f;
    for (int k = kb0; k < kb0 + 64; ++k) {
      float w = pa.w_ss1[(size_t)k * 4608 + n];
      a0 += pa.tin[k] * w;
      a1 += pa.tin[768 + k] * w;
    }
    atomicAdd(&pa.tacc1[n], a0);
    atomicAdd(&pa.tacc1[4608 + n], a1);
  }
}

// ---------------------------------------------------------------------------
// t-path stage 2 with inline silu+bias on the input:
// teacc[b][n] += sum_k silu(tacc1[b][k]+b_ss1[k]) * w_ss2[k][n]
// Round-2: float2 W loads (was scalar; 85 MB read is the biggest single
// buffer in the pipeline).
// ---------------------------------------------------------------------------
__global__ void k_tvec2_silu(const float* __restrict__ tacc1, const float* __restrict__ bss1,
                             const float* __restrict__ W, float* __restrict__ teacc) {
  int n2 = blockIdx.x * 256 + threadIdx.x;   // float2 column index, 0..2303
  int kb = blockIdx.y * 64;
  float a0x = 0.f, a0y = 0.f, a1x = 0.f, a1y = 0.f;
  for (int k = kb; k < kb + 64; ++k) {
    float2 w = *(const float2*)&W[(size_t)k * 4608 + n2 * 2];
    float bs = bss1[k];
    float t0 = tacc1[k] + bs;
    float t1 = tacc1[4608 + k] + bs;
    t0 = t0 / (1.f + expf(-t0));
    t1 = t1 / (1.f + expf(-t1));
    a0x += t0 * w.x; a0y += t0 * w.y;
    a1x += t1 * w.x; a1y += t1 * w.y;
  }
  atomicAdd(&teacc[n2 * 2 + 0], a0x);
  atomicAdd(&teacc[n2 * 2 + 1], a0y);
  atomicAdd(&teacc[4608 + n2 * 2 + 0], a1x);
  atomicAdd(&teacc[4608 + n2 * 2 + 1], a1y);
}

// ---------------------------------------------------------------------------
// LayerNorm + adaLN modulate: out_bf16 = (teacc+bss2)[g] * LN(x) + (teacc+bss2)[b]
// ---------------------------------------------------------------------------
__global__ void k_ln_mod(const float* __restrict__ x, const float* __restrict__ lng,
                         const float* __restrict__ lnb, const float* __restrict__ teacc,
                         const float* __restrict__ bss2,
                         int gofs, int bofs, __hip_bfloat16* __restrict__ out) {
  int row = blockIdx.x;          // 0..4095
  int b = row >> 11;             // / 2048
  const float* xr = x + (size_t)row * 768;
  int tid = threadIdx.x;
  float v[3];
  float s = 0.f, sq = 0.f;
#pragma unroll
  for (int i = 0; i < 3; ++i) { v[i] = xr[tid + 256 * i]; s += v[i]; sq += v[i] * v[i]; }
#pragma unroll
  for (int o = 32; o > 0; o >>= 1) { s += __shfl_xor(s, o); sq += __shfl_xor(sq, o); }
  __shared__ float rs[4], rq[4];
  int w = tid >> 6, lane = tid & 63;
  if (lane == 0) { rs[w] = s; rq[w] = sq; }
  __syncthreads();
  s = rs[0] + rs[1] + rs[2] + rs[3];
  sq = rq[0] + rq[1] + rq[2] + rq[3];
  float mu = s * (1.f / 768.f);
  float var = sq * (1.f / 768.f) - mu * mu;
  float rstd = rsqrtf(var + 1e-5f);
  const float* tb = teacc + (size_t)b * 4608;
#pragma unroll
  for (int i = 0; i < 3; ++i) {
    int n = tid + 256 * i;
    float gv = tb[gofs + n] + bss2[gofs + n];
    float bv = tb[bofs + n] + bss2[bofs + n];
    float h = (v[i] - mu) * rstd * lng[n] + lnb[n];
    h = gv * h + bv;
    out[(size_t)row * 768 + n] = __float2bfloat16(h);
  }
}

// ---------------------------------------------------------------------------
// m97-style bf16 MFMA GEMM: C[M,N] = A[M,K] @ Bt[N,K]^T (both [row][k]).
// Tile BM x BN, BK=64, 4 waves (2x2), global_load_lds width=16 staging,
// XOR-swizzled LDS (phys_chunk = logical ^ (row&7)).
// Epilogues: 0=bias->f32, 1=bias+gelu(tanh)->bf16, 2=res+gate*(acc+bias)->f32
//            3=qkv fused: Q scaled ->qkvb, K ->qkvb, V -> VT transposed
// ---------------------------------------------------------------------------
template <int BM, int BN, int EPI>
__global__ __launch_bounds__(256)
void k_gemm(const __hip_bfloat16* __restrict__ A,
            const __hip_bfloat16* __restrict__ Bt,
            const float* __restrict__ bias,
            float* __restrict__ outF, __hip_bfloat16* __restrict__ outB,
            __hip_bfloat16* __restrict__ outV,
            const float* __restrict__ res, const float* __restrict__ teacc,
            const float* __restrict__ bss2,
            int gofs, int M, int N, int K) {
  constexpr int MI = BM / 32;
  constexpr int NI = BN / 32;
  __shared__ __align__(16) __hip_bfloat16 As[BM * 64];
  __shared__ __align__(16) __hip_bfloat16 Bs[BN * 64];
  const int tid = threadIdx.x;
  const int w = tid >> 6, lane = tid & 63;
  const int quad = lane >> 4, l16 = lane & 15;
  const int wm = w & 1, wn = w >> 1;
  const int m0 = blockIdx.y * BM, n0 = blockIdx.x * BN;
  const int srow = lane >> 3;
  const int sco = ((lane & 7) ^ srow) * 8;

  f32x4 acc[MI][NI] = {};

  for (int k0 = 0; k0 < K; k0 += 64) {
#pragma unroll
    for (int ii = 0; ii < BM / 32; ++ii) {
      int is = w * (BM / 32) + ii;
      const __hip_bfloat16* g = A + (size_t)(m0 + is * 8 + srow) * K + k0 + sco;
      __builtin_amdgcn_global_load_lds(
          (const __attribute__((address_space(1))) void*)g,
          (__attribute__((address_space(3))) void*)&As[is * 512], 16, 0, 0);
    }
#pragma unroll
    for (int ii = 0; ii < BN / 32; ++ii) {
      int is = w * (BN / 32) + ii;
      const __hip_bfloat16* g = Bt + (size_t)(n0 + is * 8 + srow) * K + k0 + sco;
      __builtin_amdgcn_global_load_lds(
          (const __attribute__((address_space(1))) void*)g,
          (__attribute__((address_space(3))) void*)&Bs[is * 512], 16, 0, 0);
    }
    __syncthreads();
#pragma unroll
    for (int ks = 0; ks < 2; ++ks) {
      bf16x8 af[MI], bfv[NI];
#pragma unroll
      for (int i = 0; i < MI; ++i) {
        int row = wm * (BM / 2) + i * 16 + l16;
        int cph = (ks * 4 + quad) ^ (row & 7);
        af[i] = *(const bf16x8*)&As[row * 64 + cph * 8];
      }
#pragma unroll
      for (int j = 0; j < NI; ++j) {
        int row = wn * (BN / 2) + j * 16 + l16;
        int cph = (ks * 4 + quad) ^ (row & 7);
        bfv[j] = *(const bf16x8*)&Bs[row * 64 + cph * 8];
      }
#pragma unroll
      for (int i = 0; i < MI; ++i)
#pragma unroll
        for (int j = 0; j < NI; ++j)
          acc[i][j] = __builtin_amdgcn_mfma_f32_16x16x32_bf16(af[i], bfv[j], acc[i][j], 0, 0, 0);
    }
    __syncthreads();
  }

#pragma unroll
  for (int j = 0; j < NI; ++j) {
    int col = n0 + wn * (BN / 2) + j * 16 + l16;
    float bs = bias[col];
#pragma unroll
    for (int i = 0; i < MI; ++i) {
      int row0 = m0 + wm * (BM / 2) + i * 16 + quad * 4;
      if (EPI == 3 && col >= 1536) {
        // V head: write transposed into VT[(b*12+nh)*64+dl][token], 8B packed
        int d = col - 1536;
        int nh = d >> 6, dl = d & 63;
        int bb = row0 >> 11, tok = row0 & 2047;
        __hip_bfloat16 tmp[4];
#pragma unroll
        for (int r = 0; r < 4; ++r) tmp[r] = __float2bfloat16(acc[i][j][r] + bs);
        *(uint2*)&outV[((size_t)(bb * 12 + nh) * 64 + dl) * 2048 + tok] = *(uint2*)tmp;
      } else {
#pragma unroll
        for (int r = 0; r < 4; ++r) {
          int row = row0 + r;
          float v = acc[i][j][r] + bs;
          size_t idx = (size_t)row * N + col;
          if (EPI == 0) {
            outF[idx] = v;
          } else if (EPI == 1) {
            // tanh-approx gelu: v - v/(e+1), e = exp2(2*log2e*0.79788456*(v+0.044715 v^3))
            float v2 = v * v;
            float u = v * (0.79788456080286536f + 0.035677408136300125f * v2);
            float e = fast_exp2(u * 2.8853900817779268f);
            float gl = v - v * __builtin_amdgcn_rcpf(e + 1.f);
            outB[idx] = __float2bfloat16(gl);
          } else if (EPI == 2) {
            float gate = teacc[(size_t)(row >> 11) * 4608 + gofs + col] + bss2[gofs + col];
            outF[idx] = res[idx] + gate * v;
          } else {  // EPI==3, Q/K heads
            float vq = (col < 768) ? v * SCALE_Q_LOG2E : v;
            outB[idx] = __float2bfloat16(vq);
          }
        }
      }
    }
  }
}

// ---------------------------------------------------------------------------
// MFMA flash attention — counted-vmcnt pipelined version (round-1; k_attn
// dropped out of the top-5 dispatches with this, keep).
//  * Ks double-buffered (Ks[2]); V[kt] + K[kt+1] issued at top of tile kt so
//    staging latency hides under QK^T (K) and QK^T+exp2/P-pack (V).
//  * Raw s_barrier + counted s_waitcnt vmcnt(8)/vmcnt(4) (never 0 in steady
//    state) instead of __syncthreads' full vmcnt(0) drain.
//  * Per-wave P buffer aliased into Ks[cur] (wave w's K-staging region ==
//    its 4KB P region), legal after the post-QK^T barrier. LDS stays 48KB.
//  * s_setprio(1) around the MFMA clusters (T5; attn-positive per m191).
// ---------------------------------------------------------------------------
__launch_bounds__(256)
__global__ void k_attn(const __hip_bfloat16* __restrict__ qkvb,
                       const __hip_bfloat16* __restrict__ VT,
                       __hip_bfloat16* __restrict__ out) {
  __shared__ __align__(16) __hip_bfloat16 Ks[2][128 * 64];  // [s][d], 8-chunk swizzle; Ks[cur] doubles as P
  __shared__ __align__(16) __hip_bfloat16 Vs[64 * 128];     // [d][s], 16-chunk swizzle

  const int tid = threadIdx.x;
  const int w = tid >> 6, lane = tid & 63;
  const int quad = lane >> 4, l16 = lane & 15;
  const int qt = blockIdx.x, nh = blockIdx.y, b = blockIdx.z;
  const int bh = b * 12 + nh;

  const int qrow0 = b * 2048 + qt * 64 + w * 16;
  bf16x8 qf[2];
#pragma unroll
  for (int t = 0; t < 2; ++t)
    qf[t] = *(const bf16x8*)(qkvb + (size_t)(qrow0 + l16) * 2304 + nh * 64 + t * 32 + quad * 8);
  // Retire the Q loads now so the in-loop vmcnt ledger counts only staging.
  asm volatile("s_waitcnt vmcnt(0)" ::: "memory");

  bf16x8 ones;
#pragma unroll
  for (int j = 0; j < 8; ++j) ones[j] = (__bf16)1.0f;

  f32x4 o[4] = {};   // col = nf*16+l16, row = quad*4+r
  f32x4 o_l = {};    // row sums (replicated over cols)

  const int srow8 = lane >> 3;               // K staging: 8 rows/instr
  const int sco8 = ((lane & 7) ^ srow8) * 8;
  const int srow4 = lane >> 4;               // V staging: 4 rows/instr

  // prologue: stage K[0] -> Ks[0]   (outstanding: 4)
#pragma unroll
  for (int ii = 0; ii < 4; ++ii) {
    int i = w * 4 + ii;
    const __hip_bfloat16* gk =
        qkvb + (size_t)(b * 2048 + i * 8 + srow8) * 2304 + 768 + nh * 64 + sco8;
    __builtin_amdgcn_global_load_lds(
        (const __attribute__((address_space(1))) void*)gk,
        (__attribute__((address_space(3))) void*)&Ks[0][i * 512], 16, 0, 0);
  }

#pragma unroll 1
  for (int kt = 0; kt < 16; ++kt) {
    const int cur = kt & 1;

    // B_consume: all waves done reading Vs / P-in-Ks[cur^1] from prev tile.
    asm volatile("s_waitcnt lgkmcnt(0)" ::: "memory");
    __builtin_amdgcn_s_barrier();

    // issue V[kt] -> Vs              (outstanding: 4 -> 8)
#pragma unroll
    for (int ii = 0; ii < 4; ++ii) {
      int i = w * 4 + ii;
      int vrow = i * 4 + srow4;
      const __hip_bfloat16* gv =
          VT + (size_t)(bh * 64 + vrow) * 2048 + kt * 128 + (((lane & 15) ^ (vrow & 15)) * 8);
      __builtin_amdgcn_global_load_lds(
          (const __attribute__((address_space(1))) void*)gv,
          (__attribute__((address_space(3))) void*)&Vs[i * 512], 16, 0, 0);
    }
    // issue K[kt+1] -> Ks[cur^1]     (outstanding: 8 -> 12)
    if (kt < 15) {
#pragma unroll
      for (int ii = 0; ii < 4; ++ii) {
        int i = w * 4 + ii;
        const __hip_bfloat16* gk =
            qkvb + (size_t)(b * 2048 + (kt + 1) * 128 + i * 8 + srow8) * 2304 + 768 + nh * 64 + sco8;
        __builtin_amdgcn_global_load_lds(
            (const __attribute__((address_space(1))) void*)gk,
            (__attribute__((address_space(3))) void*)&Ks[cur ^ 1][i * 512], 16, 0, 0);
      }
      asm volatile("s_waitcnt vmcnt(8)" ::: "memory");   // K[kt] retired
    } else {
      asm volatile("s_waitcnt vmcnt(4)" ::: "memory");   // K[15] retired (only V in flight)
    }
    __builtin_amdgcn_s_barrier();                        // B_Kready

    // ---- S = Q K^T : 16 q-rows x 128 s-cols per wave ----
    f32x4 s_acc[8] = {};
    __builtin_amdgcn_s_setprio(1);
#pragma unroll
    for (int t = 0; t < 2; ++t) {
#pragma unroll
      for (int c = 0; c < 8; ++c) {
        int row = c * 16 + l16;
        int cph = (t * 4 + quad) ^ (row & 7);
        bf16x8 kf = *(const bf16x8*)&Ks[cur][row * 64 + cph * 8];
        s_acc[c] = __builtin_amdgcn_mfma_f32_16x16x32_bf16(qf[t], kf, s_acc[c], 0, 0, 0);
      }
    }
    __builtin_amdgcn_s_setprio(0);

    // B_QKdone: all waves finished reading Ks[cur]; it may now take P.
    asm volatile("s_waitcnt lgkmcnt(0)" ::: "memory");
    __builtin_amdgcn_s_barrier();

    // ---- P = exp2(S') -> per-wave region of Ks[cur] (swizzled writes) ----
    __hip_bfloat16* Pb = &Ks[cur][w * 2048];
#pragma unroll
    for (int c = 0; c < 8; ++c) {
      int chunk = c * 2 + (l16 >> 3);
#pragma unroll
      for (int r = 0; r < 4; ++r) {
        float p = fast_exp2(s_acc[c][r]);
        int row = quad * 4 + r;
        int phys = chunk ^ row;
        Pw_dummy:;
        Pb[row * 128 + phys * 8 + (l16 & 7)] = __float2bfloat16(p);
      }
    }

    // V[kt] retired (K[kt+1] stays in flight across the barrier); own P visible.
    if (kt < 15) asm volatile("s_waitcnt vmcnt(4)" ::: "memory");
    else         asm volatile("s_waitcnt vmcnt(0)" ::: "memory");
    asm volatile("s_waitcnt lgkmcnt(0)" ::: "memory");
    __builtin_amdgcn_s_barrier();                        // B_Vready

    // ---- O += P V, l += P @ ones ----
    __builtin_amdgcn_s_setprio(1);
#pragma unroll
    for (int t2 = 0; t2 < 4; ++t2) {
      int phys_p = ((t2 * 4 + quad) ^ l16);
      bf16x8 pa = *(const bf16x8*)&Pb[l16 * 128 + phys_p * 8];
#pragma unroll
      for (int nf = 0; nf < 4; ++nf) {
        int row = nf * 16 + l16;
        int cph = (t2 * 4 + quad) ^ (row & 15);
        bf16x8 vf = *(const bf16x8*)&Vs[row * 128 + cph * 8];
        o[nf] = __builtin_amdgcn_mfma_f32_16x16x32_bf16(pa, vf, o[nf], 0, 0, 0);
      }
      o_l = __builtin_amdgcn_mfma_f32_16x16x32_bf16(pa, ones, o_l, 0, 0, 0);
    }
    __builtin_amdgcn_s_setprio(0);
  }

  // ---- epilogue: O / l ----
  {
    float inv[4];
#pragma unroll
    for (int r = 0; r < 4; ++r) inv[r] = 1.f / o_l[r];
#pragma unroll
    for (int nf = 0; nf < 4; ++nf)
#pragma unroll
      for (int r = 0; r < 4; ++r) {
        int row = qrow0 + quad * 4 + r;
        out[(size_t)row * 768 + nh * 64 + nf * 16 + l16] = __float2bfloat16(o[nf][r] * inv[r]);
      }
  }
}

// ---------------------------------------------------------------------------
extern "C" void kernel_launch(void* const* d_in, const int* in_sizes, int n_in,
                              void* d_out, int out_size, void* d_ws, size_t ws_size,
                              hipStream_t stream) {
  const float* x      = (const float*)d_in[0];
  const float* t      = (const float*)d_in[1];
  const float* w_qkv  = (const float*)d_in[2];
  const float* b_qkv  = (const float*)d_in[3];
  const float* w_m1   = (const float*)d_in[4];
  const float* b_m1   = (const float*)d_in[5];
  const float* w_m2   = (const float*)d_in[6];
  const float* b_m2   = (const float*)d_in[7];
  const float* w_ss1  = (const float*)d_in[8];
  const float* b_ss1  = (const float*)d_in[9];
  const float* w_ss2  = (const float*)d_in[10];
  const float* b_ss2  = (const float*)d_in[11];
  const float* ln1_g  = (const float*)d_in[12];
  const float* ln1_b  = (const float*)d_in[13];
  const float* ln2_g  = (const float*)d_in[14];
  const float* ln2_b  = (const float*)d_in[15];
  const float* w_f1   = (const float*)d_in[16];
  const float* b_f1   = (const float*)d_in[17];
  const float* w_f2   = (const float*)d_in[18];
  const float* b_f2   = (const float*)d_in[19];
  float* out = (float*)d_out;

  char* ws = (char*)d_ws;
  size_t off = 0;
  auto alloc = [&](size_t bytes) -> char* {
    off = (off + 255) & ~(size_t)255;
    char* p = ws + off;
    off += bytes;
    return p;
  };
  __hip_bfloat16* wtq  = (__hip_bfloat16*)alloc((size_t)2304 * 768 * 2);
  __hip_bfloat16* wtm1 = (__hip_bfloat16*)alloc((size_t)3072 * 768 * 2);
  __hip_bfloat16* wtm2 = (__hip_bfloat16*)alloc((size_t)768 * 3072 * 2);
  __hip_bfloat16* wtf1 = (__hip_bfloat16*)alloc((size_t)3072 * 768 * 2);
  __hip_bfloat16* wtf2 = (__hip_bfloat16*)alloc((size_t)768 * 3072 * 2);
  float* tacc1 = (float*)alloc(9216 * 4);
  float* teacc = (float*)alloc(9216 * 4);
  __hip_bfloat16* h1   = (__hip_bfloat16*)alloc((size_t)4096 * 768 * 2);   // reused as h2
  __hip_bfloat16* qkvb = (__hip_bfloat16*)alloc((size_t)4096 * 2304 * 2);
  __hip_bfloat16* VT   = (__hip_bfloat16*)alloc((size_t)24 * 64 * 2048 * 2);
  __hip_bfloat16* attn = (__hip_bfloat16*)alloc((size_t)4096 * 768 * 2);
  __hip_bfloat16* act1 = (__hip_bfloat16*)alloc((size_t)4096 * 3072 * 2);  // reused as act2
  float* x1            = (float*)alloc((size_t)4096 * 768 * 4);

  (void)hipMemsetAsync(tacc1, 0, 9216 * 4, stream);
  (void)hipMemsetAsync(teacc, 0, 9216 * 4, stream);

  // prep: 5 weight transposes (64x64 tiles) + t-path stage 1
  PrepArgs pa;
  pa.src[0] = w_qkv; pa.dst[0] = wtq;  pa.K[0] = 768;  pa.N[0] = 2304;
  pa.src[1] = w_m1;  pa.dst[1] = wtm1; pa.K[1] = 768;  pa.N[1] = 3072;
  pa.src[2] = w_m2;  pa.dst[2] = wtm2; pa.K[2] = 3072; pa.N[2] = 768;
  pa.src[3] = w_f1;  pa.dst[3] = wtf1; pa.K[3] = 768;  pa.N[3] = 3072;
  pa.src[4] = w_f2;  pa.dst[4] = wtf2; pa.K[4] = 3072; pa.N[4] = 768;
  pa.start[0] = 0;
  pa.start[1] = pa.start[0] + (2304 / 64) * (768 / 64);
  pa.start[2] = pa.start[1] + (3072 / 64) * (768 / 64);
  pa.start[3] = pa.start[2] + (768 / 64) * (3072 / 64);
  pa.start[4] = pa.start[3] + (3072 / 64) * (768 / 64);
  pa.start[5] = pa.start[4] + (768 / 64) * (3072 / 64);
  pa.tin = t; pa.w_ss1 = w_ss1; pa.tacc1 = tacc1;
  int tvec1_blocks = 18 * 12;  // (4608/256) x (768/64)
  k_prep<<<pa.start[5] + tvec1_blocks, 256, 0, stream>>>(pa);

  // t-path stage 2 (silu+bias inline, float2 loads)
  k_tvec2_silu<<<dim3(4608 / 512, 4608 / 64), 256, 0, stream>>>(tacc1, b_ss1, w_ss2, teacc);

  // block 1: LN1+mod -> qkv GEMM (Q scaled, V transposed to VT) -> attn -> mFFN
  k_ln_mod<<<4096, 256, 0, stream>>>(x, ln1_g, ln1_b, teacc, b_ss2, 0, 768, h1);
  k_gemm<64, 128, 3><<<dim3(2304 / 128, 4096 / 64), 256, 0, stream>>>(
      h1, wtq, b_qkv, nullptr, qkvb, VT, nullptr, nullptr, nullptr, 0, 4096, 2304, 768);
  k_attn<<<dim3(32, 12, 2), 256, 0, stream>>>(qkvb, VT, attn);
  k_gemm<128, 128, 1><<<dim3(3072 / 128, 4096 / 128), 256, 0, stream>>>(
      attn, wtm1, b_m1, nullptr, act1, nullptr, nullptr, nullptr, nullptr, 0, 4096, 3072, 768);
  k_gemm<64, 128, 2><<<dim3(768 / 128, 4096 / 64), 256, 0, stream>>>(
      act1, wtm2, b_m2, x1, nullptr, nullptr, x, teacc, b_ss2, 1536, 4096, 768, 3072);

  // block 2: LN2+mod -> FFN
  k_ln_mod<<<4096, 256, 0, stream>>>(x1, ln2_g, ln2_b, teacc, b_ss2, 2304, 3072, h1);
  k_gemm<128, 128, 1><<<dim3(3072 / 128, 4096 / 128), 256, 0, stream>>>(
      h1, wtf1, b_f1, nullptr, act1, nullptr, nullptr, nullptr, nullptr, 0, 4096, 3072, 768);
  k_gemm<64, 128, 2><<<dim3(768 / 128, 4096 / 64), 256, 0, stream>>>(
      act1, wtf2, b_f2, out, nullptr, nullptr, x1, teacc, b_ss2, 3840, 4096, 768, 3072);
}